// Round 1
// baseline (1522.511 us; speedup 1.0000x reference)
//
#include <hip/hip_runtime.h>
#include <hip/hip_bf16.h>
#include <stdint.h>

#define BETA 0.5f
#define IGNORE_INDEX (-100)

typedef short bf16x8 __attribute__((ext_vector_type(8)));
typedef float f32x4 __attribute__((ext_vector_type(4)));

// ---------------------------------------------------------------- converts
__global__ __launch_bounds__(256) void f32_to_bf16_kernel(
    const float* __restrict__ in, uint16_t* __restrict__ out, int n) {
  int i = (blockIdx.x * blockDim.x + threadIdx.x) * 4;
  const int stride = gridDim.x * blockDim.x * 4;
  for (; i < n; i += stride) {
    float4 v = *reinterpret_cast<const float4*>(in + i);
    __hip_bfloat16 b0 = __float2bfloat16(v.x);
    __hip_bfloat16 b1 = __float2bfloat16(v.y);
    __hip_bfloat16 b2 = __float2bfloat16(v.z);
    __hip_bfloat16 b3 = __float2bfloat16(v.w);
    ushort4 o;
    o.x = *reinterpret_cast<const uint16_t*>(&b0);
    o.y = *reinterpret_cast<const uint16_t*>(&b1);
    o.z = *reinterpret_cast<const uint16_t*>(&b2);
    o.w = *reinterpret_cast<const uint16_t*>(&b3);
    *reinterpret_cast<ushort4*>(out + i) = o;
  }
}

// ---------------------------------------------------------------- GEMM (NT)
// C[n][v] = sum_k A[n][k] * B[v][k].  A:[N][K] bf16, B:[V][K] bf16, C bf16.
// m97 structure: 128x128 tile, BK=32, 4 waves (2x2), global_load_lds w=16.
__global__ __launch_bounds__(256) void gemm_bt_kernel(
    const uint16_t* __restrict__ A, const uint16_t* __restrict__ B,
    uint16_t* __restrict__ C, int K, int V) {
  __shared__ __align__(16) uint16_t As[128 * 32];
  __shared__ __align__(16) uint16_t Bs[128 * 32];

  const int n0 = blockIdx.x * 128;
  const int v0 = blockIdx.y * 128;
  const int t = threadIdx.x;
  const int lane = t & 63;
  const int wave = t >> 6;
  const int w0 = wave >> 1;        // wave row (0..1)
  const int w1 = wave & 1;         // wave col (0..1)
  const int wl = lane & 15;        // fragment row/col selector
  const int kg = lane >> 4;        // k-group (0..3), 8 elems each

  // staging: each thread loads 16B; 4 lanes per 32-elem row; 64 rows/round
  const int srow = t >> 2;         // 0..63
  const int scol = (t & 3) * 8;    // 0,8,16,24

  f32x4 acc[4][4] = {};

  const int nK = K >> 5;
  for (int kt = 0; kt < nK; ++kt) {
    const int k0 = kt * 32;
    __syncthreads();
#pragma unroll
    for (int r = 0; r < 2; ++r) {
      const int row = r * 64 + srow;
      __builtin_amdgcn_global_load_lds(
          (const __attribute__((address_space(1))) void*)(A + (size_t)(n0 + row) * K + k0 + scol),
          (__attribute__((address_space(3))) void*)(As + row * 32 + scol), 16, 0, 0);
      __builtin_amdgcn_global_load_lds(
          (const __attribute__((address_space(1))) void*)(B + (size_t)(v0 + row) * K + k0 + scol),
          (__attribute__((address_space(3))) void*)(Bs + row * 32 + scol), 16, 0, 0);
    }
    __syncthreads();

    bf16x8 af[4], bfg[4];
#pragma unroll
    for (int m = 0; m < 4; ++m)
      af[m] = *reinterpret_cast<const bf16x8*>(As + (w0 * 64 + m * 16 + wl) * 32 + kg * 8);
#pragma unroll
    for (int n = 0; n < 4; ++n)
      bfg[n] = *reinterpret_cast<const bf16x8*>(Bs + (w1 * 64 + n * 16 + wl) * 32 + kg * 8);
#pragma unroll
    for (int m = 0; m < 4; ++m)
#pragma unroll
      for (int n = 0; n < 4; ++n)
        acc[m][n] = __builtin_amdgcn_mfma_f32_16x16x32_bf16(af[m], bfg[n], acc[m][n], 0, 0, 0);
  }

  // epilogue: C/D layout col=lane&15, row=(lane>>4)*4+reg  [m89/m91 verified]
#pragma unroll
  for (int m = 0; m < 4; ++m)
#pragma unroll
    for (int n = 0; n < 4; ++n)
#pragma unroll
      for (int r = 0; r < 4; ++r) {
        const int row = n0 + w0 * 64 + m * 16 + kg * 4 + r;
        const int col = v0 + w1 * 64 + n * 16 + wl;
        __hip_bfloat16 b = __float2bfloat16(acc[m][n][r]);
        C[(size_t)row * V + col] = *reinterpret_cast<const uint16_t*>(&b);
      }
}

// ---------------------------------------------------------------- JSD rows
__device__ __forceinline__ void unpack8(uint4 v, float* f) {
  uint32_t w[4] = {v.x, v.y, v.z, v.w};
#pragma unroll
  for (int j = 0; j < 4; ++j) {
    union { uint32_t u; float x; } lo, hi;
    lo.u = (w[j] & 0xffffu) << 16;
    hi.u = w[j] & 0xffff0000u;
    f[2 * j] = lo.x;
    f[2 * j + 1] = hi.x;
  }
}

__device__ __forceinline__ float blockReduce(float v, bool isMax, float* sh) {
#pragma unroll
  for (int o = 32; o >= 1; o >>= 1) {
    float other = __shfl_xor(v, o, 64);
    v = isMax ? fmaxf(v, other) : (v + other);
  }
  const int w = threadIdx.x >> 6;
  __syncthreads();
  if ((threadIdx.x & 63) == 0) sh[w] = v;
  __syncthreads();
  float r = sh[0];
#pragma unroll
  for (int i = 1; i < 4; ++i) r = isMax ? fmaxf(r, sh[i]) : (r + sh[i]);
  return r;
}

__global__ __launch_bounds__(256) void jsd_rows_kernel(
    const uint16_t* __restrict__ SL, const uint16_t* __restrict__ TL,
    float* __restrict__ per_tok, int V) {
  __shared__ __align__(16) uint16_t rowS[32000];
  __shared__ __align__(16) uint16_t rowT[32000];
  __shared__ float red[4];

  const int t = threadIdx.x;
  const int row = blockIdx.x;
  const uint4* gS = reinterpret_cast<const uint4*>(SL + (size_t)row * V);
  const uint4* gT = reinterpret_cast<const uint4*>(TL + (size_t)row * V);
  uint4* lS = reinterpret_cast<uint4*>(rowS);
  uint4* lT = reinterpret_cast<uint4*>(rowT);
  const int nvec = V >> 3;  // 4000

  for (int i = t; i < nvec; i += 256) { lS[i] = gS[i]; lT[i] = gT[i]; }
  __syncthreads();

  // pass 1: max
  float mS = -3.0e38f, mT = -3.0e38f;
  for (int i = t; i < nvec; i += 256) {
    float fs[8], ft[8];
    unpack8(lS[i], fs);
    unpack8(lT[i], ft);
#pragma unroll
    for (int j = 0; j < 8; ++j) { mS = fmaxf(mS, fs[j]); mT = fmaxf(mT, ft[j]); }
  }
  mS = blockReduce(mS, true, red);
  mT = blockReduce(mT, true, red);

  // pass 2: sum exp
  float sS = 0.f, sT = 0.f;
  for (int i = t; i < nvec; i += 256) {
    float fs[8], ft[8];
    unpack8(lS[i], fs);
    unpack8(lT[i], ft);
#pragma unroll
    for (int j = 0; j < 8; ++j) { sS += __expf(fs[j] - mS); sT += __expf(ft[j] - mT); }
  }
  sS = blockReduce(sS, false, red);
  sT = blockReduce(sT, false, red);
  const float lseS = mS + __logf(sS);
  const float lseT = mT + __logf(sT);

  // pass 3: JSD accumulation (student->Q, teacher->P)
  float acc = 0.f;
  for (int i = t; i < nvec; i += 256) {
    float fs[8], ft[8];
    unpack8(lS[i], fs);
    unpack8(lT[i], ft);
#pragma unroll
    for (int j = 0; j < 8; ++j) {
      const float lq = fs[j] - lseS;
      const float lp = ft[j] - lseT;
      const float q = __expf(lq);
      const float p = __expf(lp);
      const float m = BETA * p + (1.f - BETA) * q;
      const float lm = __logf(m);
      acc += BETA * p * (lp - lm) + (1.f - BETA) * q * (lq - lm);
    }
  }
  acc = blockReduce(acc, false, red);
  if (t == 0) per_tok[row] = acc;
}

// ---------------------------------------------------------------- finalize
__global__ __launch_bounds__(256) void finalize_kernel(
    const float* __restrict__ per_tok, const int* __restrict__ tgt,
    float* __restrict__ out, int N) {
  __shared__ float redf[4];
  __shared__ int redi[4];
  float s = 0.f;
  int c = 0;
  for (int i = threadIdx.x; i < N; i += 256) {
    if (tgt[i] != IGNORE_INDEX) { s += per_tok[i]; c += 1; }
  }
#pragma unroll
  for (int o = 32; o >= 1; o >>= 1) {
    s += __shfl_xor(s, o, 64);
    c += __shfl_xor(c, o, 64);
  }
  const int w = threadIdx.x >> 6;
  if ((threadIdx.x & 63) == 0) { redf[w] = s; redi[w] = c; }
  __syncthreads();
  if (threadIdx.x == 0) {
    float st = 0.f;
    int ct = 0;
#pragma unroll
    for (int i = 0; i < 4; ++i) { st += redf[i]; ct += redi[i]; }
    out[0] = st / (float)(ct > 0 ? ct : 1);
  }
}

// ---------------------------------------------------------------- launch
extern "C" void kernel_launch(void* const* d_in, const int* in_sizes, int n_in,
                              void* d_out, int out_size, void* d_ws, size_t ws_size,
                              hipStream_t stream) {
  const float* student = (const float*)d_in[0];
  const float* W_s     = (const float*)d_in[1];
  const float* teacher = (const float*)d_in[2];
  const float* W_t     = (const float*)d_in[3];
  const int*   target  = (const int*)d_in[4];

  const int N  = in_sizes[4];            // 2048
  const int Hs = in_sizes[0] / N;        // 2048
  const int Ht = in_sizes[2] / N;        // 4096
  const int V  = in_sizes[1] / Hs;       // 32000

  char* ws = (char*)d_ws;
  size_t off = 0;
  auto alloc = [&](size_t bytes) -> void* {
    void* p = ws + off;
    off += (bytes + 255) & ~(size_t)255;
    return p;
  };
  uint16_t* Sbf  = (uint16_t*)alloc((size_t)N * Hs * 2);
  uint16_t* Wsbf = (uint16_t*)alloc((size_t)V * Hs * 2);
  uint16_t* Tbf  = (uint16_t*)alloc((size_t)N * Ht * 2);
  uint16_t* Wtbf = (uint16_t*)alloc((size_t)V * Ht * 2);
  uint16_t* slog = (uint16_t*)alloc((size_t)N * V * 2);
  uint16_t* tlog = (uint16_t*)alloc((size_t)N * V * 2);
  float* per_tok = (float*)alloc((size_t)N * sizeof(float));
  (void)ws_size;  // total ~681 MB

  f32_to_bf16_kernel<<<1024, 256, 0, stream>>>(student, Sbf, N * Hs);
  f32_to_bf16_kernel<<<2048, 256, 0, stream>>>(W_s, Wsbf, V * Hs);
  f32_to_bf16_kernel<<<1024, 256, 0, stream>>>(teacher, Tbf, N * Ht);
  f32_to_bf16_kernel<<<2048, 256, 0, stream>>>(W_t, Wtbf, V * Ht);

  // grid.x = row tile (fastest-varying) so 16 consecutive blocks share one
  // W column-panel (1 MB) -> L2/L3 reuse of the big weight matrices.
  gemm_bt_kernel<<<dim3(N / 128, V / 128), 256, 0, stream>>>(Sbf, Wsbf, slog, Hs, V);
  gemm_bt_kernel<<<dim3(N / 128, V / 128), 256, 0, stream>>>(Tbf, Wtbf, tlog, Ht, V);

  jsd_rows_kernel<<<N, 256, 0, stream>>>(slog, tlog, per_tok, V);
  finalize_kernel<<<1, 256, 0, stream>>>(per_tok, target, (float*)d_out, N);
}

// Round 2
// 1219.803 us; speedup vs baseline: 1.2482x; 1.2482x over previous
//
#include <hip/hip_runtime.h>
#include <hip/hip_bf16.h>
#include <stdint.h>

#define BETA 0.5f
#define IGNORE_INDEX (-100)

typedef short bf16x8 __attribute__((ext_vector_type(8)));
typedef float f32x4 __attribute__((ext_vector_type(4)));

// ---------------------------------------------------------------- converts
__global__ __launch_bounds__(256) void f32_to_bf16_kernel(
    const float* __restrict__ in, uint16_t* __restrict__ out, int n) {
  int i = (blockIdx.x * blockDim.x + threadIdx.x) * 4;
  const int stride = gridDim.x * blockDim.x * 4;
  for (; i < n; i += stride) {
    float4 v = *reinterpret_cast<const float4*>(in + i);
    __hip_bfloat16 b0 = __float2bfloat16(v.x);
    __hip_bfloat16 b1 = __float2bfloat16(v.y);
    __hip_bfloat16 b2 = __float2bfloat16(v.z);
    __hip_bfloat16 b3 = __float2bfloat16(v.w);
    ushort4 o;
    o.x = *reinterpret_cast<const uint16_t*>(&b0);
    o.y = *reinterpret_cast<const uint16_t*>(&b1);
    o.z = *reinterpret_cast<const uint16_t*>(&b2);
    o.w = *reinterpret_cast<const uint16_t*>(&b3);
    *reinterpret_cast<ushort4*>(out + i) = o;
  }
}

// ---------------------------------------------------------------- GEMM (NT)
// C[n][v] = sum_k A[n][k] * B[v][k].  A:[M][K] bf16, B:[V][K] bf16, C bf16.
// 256x256 tile, BK=32, 8 waves (2Mx4N), 4-deep LDS ring (128 KiB),
// 2 phases/K-tile, staging 3 K-tiles ahead, counted vmcnt (T3+T4),
// setprio around MFMA clusters (T5), XOR bank swizzle via pre-swizzled
// global source + swizzled ds_read (T2, rule #21), XCD block swizzle (T1).
//
// Swizzle: granule(r,kg) = r*4 + (kg ^ s(r)), s(r) = (r + (r>>2)) & 3.
// Quarter-wave (16 lanes, fixed kg) then covers all 8 bank-quads 2x -> free.
#define BK 32
#define NBUF 4
// per buffer: A 256*32*2B = 16 KiB (1024 granules), B same. stride 32 KiB.

__global__ __launch_bounds__(512, 2) void gemm8_kernel(
    const uint16_t* __restrict__ A, const uint16_t* __restrict__ B,
    uint16_t* __restrict__ C, int K, int V, int RT, int CT) {
  __shared__ __align__(16) uint16_t lds[65536];  // 128 KiB

  // ---- block swizzle: XCD-contiguous chunks, row-tile fastest
  const int nwg = RT * CT;
  int b = blockIdx.x;
  int L;
  if ((nwg & 7) == 0) {
    L = (b & 7) * (nwg >> 3) + (b >> 3);
  } else {
    L = b;
  }
  const int rt = L % RT;
  const int ct = L / RT;
  const int row0 = rt * 256;
  const int col0 = ct * 256;

  const int t_ = threadIdx.x;
  const int w = t_ >> 6;          // wave 0..7
  const int l = t_ & 63;          // lane
  const int wl = l & 15;          // fragment row selector
  const int kg = l >> 4;          // k-granule 0..3
  const int wr = w >> 2;          // wave row 0..1 (128 rows each)
  const int wc = w & 3;           // wave col 0..3 (64 cols each)

  const int nK = K / BK;

  // ---- staging: per K-tile, 2 A-loads + 2 B-loads per thread (16B each).
  // LDS dest is linear granule order; global source is inverse-swizzled.
  // Precompute per-thread loop-invariant parts.
  int  g0 = 0 * 512 + w * 64 + l;       // granule for load 0
  int  g1 = 1 * 512 + w * 64 + l;       // granule for load 1
  int  rA0 = g0 >> 2, rA1 = g1 >> 2;
  int  sA0 = (rA0 + (rA0 >> 2)) & 3, sA1 = (rA1 + (rA1 >> 2)) & 3;
  int  ksA0 = (g0 & 3) ^ sA0, ksA1 = (g1 & 3) ^ sA1;
  const uint16_t* srcA0 = A + (size_t)(row0 + rA0) * K + ksA0 * 8;
  const uint16_t* srcA1 = A + (size_t)(row0 + rA1) * K + ksA1 * 8;
  const uint16_t* srcB0 = B + (size_t)(col0 + rA0) * K + ksA0 * 8;
  const uint16_t* srcB1 = B + (size_t)(col0 + rA1) * K + ksA1 * 8;
  uint16_t* dstA0 = lds + g0 * 8;          // + buf*16384
  uint16_t* dstA1 = lds + g1 * 8;
  uint16_t* dstB0 = lds + 8192 + g0 * 8;
  uint16_t* dstB1 = lds + 8192 + g1 * 8;

#define STAGE_A(tt)                                                          \
  do {                                                                       \
    const int _buf = (tt) & 3;                                               \
    const int _k0 = (tt) * BK;                                               \
    __builtin_amdgcn_global_load_lds(                                        \
        (const __attribute__((address_space(1))) void*)(srcA0 + _k0),        \
        (__attribute__((address_space(3))) void*)(dstA0 + _buf * 16384), 16, 0, 0); \
    __builtin_amdgcn_global_load_lds(                                        \
        (const __attribute__((address_space(1))) void*)(srcA1 + _k0),        \
        (__attribute__((address_space(3))) void*)(dstA1 + _buf * 16384), 16, 0, 0); \
  } while (0)
#define STAGE_B(tt)                                                          \
  do {                                                                       \
    const int _buf = (tt) & 3;                                               \
    const int _k0 = (tt) * BK;                                               \
    __builtin_amdgcn_global_load_lds(                                        \
        (const __attribute__((address_space(1))) void*)(srcB0 + _k0),        \
        (__attribute__((address_space(3))) void*)(dstB0 + _buf * 16384), 16, 0, 0); \
    __builtin_amdgcn_global_load_lds(                                        \
        (const __attribute__((address_space(1))) void*)(srcB1 + _k0),        \
        (__attribute__((address_space(3))) void*)(dstB1 + _buf * 16384), 16, 0, 0); \
  } while (0)

  // ---- ds_read fragment offsets (uint16 units), loop-invariant per thread.
  // A frag m: row r = wr*128 + m*16 + wl; granule = r*4 + (kg ^ s(r)).
  int offA[8], offB[4];
#pragma unroll
  for (int m = 0; m < 8; ++m) {
    int r = wr * 128 + m * 16 + wl;
    int s = (r + (r >> 2)) & 3;
    offA[m] = (r * 4 + (kg ^ s)) * 8;
  }
#pragma unroll
  for (int n = 0; n < 4; ++n) {
    int r = wc * 64 + n * 16 + wl;
    int s = (r + (r >> 2)) & 3;
    offB[n] = 8192 + (r * 4 + (kg ^ s)) * 8;
  }

  f32x4 acc[8][4] = {};

  // ---- prologue: stage tiles 0,1,2 (12 loads); wait tile 0 (vmcnt 8)
#pragma unroll
  for (int pt = 0; pt < 3; ++pt) {
    if (pt < nK) { STAGE_A(pt); STAGE_B(pt); }
  }
  asm volatile("s_waitcnt vmcnt(8)" ::: "memory");
  __builtin_amdgcn_s_barrier();
  __builtin_amdgcn_sched_barrier(0);

  for (int t = 0; t < nK; ++t) {
    const int cur = t & 3;
    const uint16_t* bufp = lds + cur * 16384;
    const bool stg = (t + 3) < nK;

    // ============ PHASE A: read m0..3 + all B, stage next A, MFMA Q0
    if (stg) STAGE_A(t + 3);
    bf16x8 af[4], bf[4];
#pragma unroll
    for (int m = 0; m < 4; ++m)
      af[m] = *reinterpret_cast<const bf16x8*>(bufp + offA[m]);
#pragma unroll
    for (int n = 0; n < 4; ++n)
      bf[n] = *reinterpret_cast<const bf16x8*>(bufp + offB[n]);
    __builtin_amdgcn_s_barrier();
    __builtin_amdgcn_s_setprio(1);
#pragma unroll
    for (int m = 0; m < 4; ++m)
#pragma unroll
      for (int n = 0; n < 4; ++n)
        acc[m][n] = __builtin_amdgcn_mfma_f32_16x16x32_bf16(af[m], bf[n], acc[m][n], 0, 0, 0);
    __builtin_amdgcn_s_setprio(0);
    __builtin_amdgcn_s_barrier();

    // ============ PHASE B: read m4..7, stage next B, MFMA Q1
    if (stg) STAGE_B(t + 3);
    bf16x8 ag[4];
#pragma unroll
    for (int m = 0; m < 4; ++m)
      ag[m] = *reinterpret_cast<const bf16x8*>(bufp + offA[4 + m]);
    __builtin_amdgcn_s_barrier();
    __builtin_amdgcn_s_setprio(1);
#pragma unroll
    for (int m = 0; m < 4; ++m)
#pragma unroll
      for (int n = 0; n < 4; ++n)
        acc[4 + m][n] = __builtin_amdgcn_mfma_f32_16x16x32_bf16(ag[m], bf[n], acc[4 + m][n], 0, 0, 0);
    __builtin_amdgcn_s_setprio(0);

    // ============ K-tile boundary: counted vmcnt, then barrier
    if (t < nK - 3) {
      asm volatile("s_waitcnt vmcnt(8)" ::: "memory");
    } else if (t == nK - 3) {
      asm volatile("s_waitcnt vmcnt(4)" ::: "memory");
    } else if (t == nK - 2) {
      asm volatile("s_waitcnt vmcnt(0)" ::: "memory");
    }
    __builtin_amdgcn_s_barrier();
    __builtin_amdgcn_sched_barrier(0);
  }

  // ---- epilogue: C/D layout col=lane&15, row=(lane>>4)*4+reg
#pragma unroll
  for (int m = 0; m < 8; ++m)
#pragma unroll
    for (int n = 0; n < 4; ++n)
#pragma unroll
      for (int r = 0; r < 4; ++r) {
        const int row = row0 + wr * 128 + m * 16 + kg * 4 + r;
        const int col = col0 + wc * 64 + n * 16 + wl;
        __hip_bfloat16 bv = __float2bfloat16(acc[m][n][r]);
        C[(size_t)row * V + col] = *reinterpret_cast<const uint16_t*>(&bv);
      }
#undef STAGE_A
#undef STAGE_B
}

// ---------------------------------------------------------------- JSD rows
__device__ __forceinline__ void unpack8(uint4 v, float* f) {
  uint32_t w[4] = {v.x, v.y, v.z, v.w};
#pragma unroll
  for (int j = 0; j < 4; ++j) {
    union { uint32_t u; float x; } lo, hi;
    lo.u = (w[j] & 0xffffu) << 16;
    hi.u = w[j] & 0xffff0000u;
    f[2 * j] = lo.x;
    f[2 * j + 1] = hi.x;
  }
}

__device__ __forceinline__ float blockReduce(float v, bool isMax, float* sh) {
#pragma unroll
  for (int o = 32; o >= 1; o >>= 1) {
    float other = __shfl_xor(v, o, 64);
    v = isMax ? fmaxf(v, other) : (v + other);
  }
  const int w = threadIdx.x >> 6;
  __syncthreads();
  if ((threadIdx.x & 63) == 0) sh[w] = v;
  __syncthreads();
  float r = sh[0];
#pragma unroll
  for (int i = 1; i < 4; ++i) r = isMax ? fmaxf(r, sh[i]) : (r + sh[i]);
  return r;
}

__global__ __launch_bounds__(256) void jsd_rows_kernel(
    const uint16_t* __restrict__ SL, const uint16_t* __restrict__ TL,
    float* __restrict__ per_tok, int V) {
  __shared__ __align__(16) uint16_t rowS[32000];
  __shared__ __align__(16) uint16_t rowT[32000];
  __shared__ float red[4];

  const int t = threadIdx.x;
  const int row = blockIdx.x;
  const uint4* gS = reinterpret_cast<const uint4*>(SL + (size_t)row * V);
  const uint4* gT = reinterpret_cast<const uint4*>(TL + (size_t)row * V);
  uint4* lS = reinterpret_cast<uint4*>(rowS);
  uint4* lT = reinterpret_cast<uint4*>(rowT);
  const int nvec = V >> 3;  // 4000

  for (int i = t; i < nvec; i += 256) { lS[i] = gS[i]; lT[i] = gT[i]; }
  __syncthreads();

  float mS = -3.0e38f, mT = -3.0e38f;
  for (int i = t; i < nvec; i += 256) {
    float fs[8], ft[8];
    unpack8(lS[i], fs);
    unpack8(lT[i], ft);
#pragma unroll
    for (int j = 0; j < 8; ++j) { mS = fmaxf(mS, fs[j]); mT = fmaxf(mT, ft[j]); }
  }
  mS = blockReduce(mS, true, red);
  mT = blockReduce(mT, true, red);

  float sS = 0.f, sT = 0.f;
  for (int i = t; i < nvec; i += 256) {
    float fs[8], ft[8];
    unpack8(lS[i], fs);
    unpack8(lT[i], ft);
#pragma unroll
    for (int j = 0; j < 8; ++j) { sS += __expf(fs[j] - mS); sT += __expf(ft[j] - mT); }
  }
  sS = blockReduce(sS, false, red);
  sT = blockReduce(sT, false, red);
  const float lseS = mS + __logf(sS);
  const float lseT = mT + __logf(sT);

  float acc = 0.f;
  for (int i = t; i < nvec; i += 256) {
    float fs[8], ft[8];
    unpack8(lS[i], fs);
    unpack8(lT[i], ft);
#pragma unroll
    for (int j = 0; j < 8; ++j) {
      const float lq = fs[j] - lseS;
      const float lp = ft[j] - lseT;
      const float q = __expf(lq);
      const float p = __expf(lp);
      const float m = BETA * p + (1.f - BETA) * q;
      const float lm = __logf(m);
      acc += BETA * p * (lp - lm) + (1.f - BETA) * q * (lq - lm);
    }
  }
  acc = blockReduce(acc, false, red);
  if (t == 0) per_tok[row] = acc;
}

// ---------------------------------------------------------------- finalize
__global__ __launch_bounds__(256) void finalize_kernel(
    const float* __restrict__ per_tok, const int* __restrict__ tgt,
    float* __restrict__ out, int N) {
  __shared__ float redf[4];
  __shared__ int redi[4];
  float s = 0.f;
  int c = 0;
  for (int i = threadIdx.x; i < N; i += 256) {
    if (tgt[i] != IGNORE_INDEX) { s += per_tok[i]; c += 1; }
  }
#pragma unroll
  for (int o = 32; o >= 1; o >>= 1) {
    s += __shfl_xor(s, o, 64);
    c += __shfl_xor(c, o, 64);
  }
  const int w = threadIdx.x >> 6;
  if ((threadIdx.x & 63) == 0) { redf[w] = s; redi[w] = c; }
  __syncthreads();
  if (threadIdx.x == 0) {
    float st = 0.f;
    int ct = 0;
#pragma unroll
    for (int i = 0; i < 4; ++i) { st += redf[i]; ct += redi[i]; }
    out[0] = st / (float)(ct > 0 ? ct : 1);
  }
}

// ---------------------------------------------------------------- launch
extern "C" void kernel_launch(void* const* d_in, const int* in_sizes, int n_in,
                              void* d_out, int out_size, void* d_ws, size_t ws_size,
                              hipStream_t stream) {
  const float* student = (const float*)d_in[0];
  const float* W_s     = (const float*)d_in[1];
  const float* teacher = (const float*)d_in[2];
  const float* W_t     = (const float*)d_in[3];
  const int*   target  = (const int*)d_in[4];

  const int N  = in_sizes[4];            // 2048
  const int Hs = in_sizes[0] / N;        // 2048
  const int Ht = in_sizes[2] / N;        // 4096
  const int V  = in_sizes[1] / Hs;       // 32000

  char* ws = (char*)d_ws;
  size_t off = 0;
  auto alloc = [&](size_t bytes) -> void* {
    void* p = ws + off;
    off += (bytes + 255) & ~(size_t)255;
    return p;
  };
  uint16_t* Sbf  = (uint16_t*)alloc((size_t)N * Hs * 2);
  uint16_t* Wsbf = (uint16_t*)alloc((size_t)V * Hs * 2);
  uint16_t* Tbf  = (uint16_t*)alloc((size_t)N * Ht * 2);
  uint16_t* Wtbf = (uint16_t*)alloc((size_t)V * Ht * 2);
  uint16_t* slog = (uint16_t*)alloc((size_t)N * V * 2);
  uint16_t* tlog = (uint16_t*)alloc((size_t)N * V * 2);
  float* per_tok = (float*)alloc((size_t)N * sizeof(float));
  (void)ws_size;  // total ~681 MB

  f32_to_bf16_kernel<<<1024, 256, 0, stream>>>(student, Sbf, N * Hs);
  f32_to_bf16_kernel<<<2048, 256, 0, stream>>>(W_s, Wsbf, V * Hs);
  f32_to_bf16_kernel<<<1024, 256, 0, stream>>>(teacher, Tbf, N * Ht);
  f32_to_bf16_kernel<<<2048, 256, 0, stream>>>(W_t, Wtbf, V * Ht);

  const int RT = N / 256;   // 8
  const int CT = V / 256;   // 125
  gemm8_kernel<<<RT * CT, 512, 0, stream>>>(Sbf, Wsbf, slog, Hs, V, RT, CT);
  gemm8_kernel<<<RT * CT, 512, 0, stream>>>(Tbf, Wtbf, tlog, Ht, V, RT, CT);

  jsd_rows_kernel<<<N, 256, 0, stream>>>(slog, tlog, per_tok, V);
  finalize_kernel<<<1, 256, 0, stream>>>(per_tok, target, (float*)d_out, N);
}

// Round 3
// 1177.210 us; speedup vs baseline: 1.2933x; 1.0362x over previous
//
#include <hip/hip_runtime.h>
#include <hip/hip_bf16.h>
#include <stdint.h>

#define BETA 0.5f
#define IGNORE_INDEX (-100)

typedef short bf16x8 __attribute__((ext_vector_type(8)));
typedef float f32x4 __attribute__((ext_vector_type(4)));

// ---------------------------------------------------------------- converts
__global__ __launch_bounds__(256) void f32_to_bf16_kernel(
    const float* __restrict__ in, uint16_t* __restrict__ out, int n) {
  int i = (blockIdx.x * blockDim.x + threadIdx.x) * 4;
  const int stride = gridDim.x * blockDim.x * 4;
  for (; i < n; i += stride) {
    float4 v = *reinterpret_cast<const float4*>(in + i);
    __hip_bfloat16 b0 = __float2bfloat16(v.x);
    __hip_bfloat16 b1 = __float2bfloat16(v.y);
    __hip_bfloat16 b2 = __float2bfloat16(v.z);
    __hip_bfloat16 b3 = __float2bfloat16(v.w);
    ushort4 o;
    o.x = *reinterpret_cast<const uint16_t*>(&b0);
    o.y = *reinterpret_cast<const uint16_t*>(&b1);
    o.z = *reinterpret_cast<const uint16_t*>(&b2);
    o.w = *reinterpret_cast<const uint16_t*>(&b3);
    *reinterpret_cast<ushort4*>(out + i) = o;
  }
}

// ---------------------------------------------------------------- GEMM (NT)
// C[n][v] = sum_k A[n][k] * B[v][k].  256x256 tile, BK=32, 8 waves (2Mx4N),
// 4-deep LDS ring (128 KiB), staging 3 K-tiles ahead, counted vmcnt (T3+T4),
// ONE barrier per K-tile (reads of buf[t-1] are retired before the boundary
// barrier via MFMA lgkm consumption, so STAGE(t+3)->buf[t-1] after the
// barrier is race-free). setprio around the MFMA cluster (T5), granule
// XOR swizzle via pre-swizzled global source (rule #21), XCD swizzle (T1).
#define BK 32

__global__ __launch_bounds__(512, 2) void gemm8_kernel(
    const uint16_t* __restrict__ A, const uint16_t* __restrict__ B,
    uint16_t* __restrict__ C, int K, int V, int RT, int CT) {
  __shared__ __align__(16) uint16_t lds[65536];  // 128 KiB

  // ---- block swizzle: XCD-contiguous chunks, row-tile fastest
  const int nwg = RT * CT;
  int b = blockIdx.x;
  int L;
  if ((nwg & 7) == 0) {
    L = (b & 7) * (nwg >> 3) + (b >> 3);
  } else {
    L = b;
  }
  const int rt = L % RT;
  const int ct = L / RT;
  const int row0 = rt * 256;
  const int col0 = ct * 256;

  const int t_ = threadIdx.x;
  const int w = t_ >> 6;          // wave 0..7
  const int l = t_ & 63;          // lane
  const int wl = l & 15;          // fragment row selector
  const int kg = l >> 4;          // k-granule 0..3
  const int wr = w >> 2;          // wave row 0..1 (128 rows each)
  const int wc = w & 3;           // wave col 0..3 (64 cols each)

  const int nK = K / BK;

  // ---- staging: 2 A-loads + 2 B-loads per thread per K-tile (16B each).
  // LDS dest linear granule order; global source inverse-swizzled.
  int  g0 = 0 * 512 + w * 64 + l;
  int  g1 = 1 * 512 + w * 64 + l;
  int  rA0 = g0 >> 2, rA1 = g1 >> 2;
  int  sA0 = (rA0 + (rA0 >> 2)) & 3, sA1 = (rA1 + (rA1 >> 2)) & 3;
  int  ksA0 = (g0 & 3) ^ sA0, ksA1 = (g1 & 3) ^ sA1;
  const uint16_t* srcA0 = A + (size_t)(row0 + rA0) * K + ksA0 * 8;
  const uint16_t* srcA1 = A + (size_t)(row0 + rA1) * K + ksA1 * 8;
  const uint16_t* srcB0 = B + (size_t)(col0 + rA0) * K + ksA0 * 8;
  const uint16_t* srcB1 = B + (size_t)(col0 + rA1) * K + ksA1 * 8;
  uint16_t* dstA0 = lds + g0 * 8;          // + buf*16384
  uint16_t* dstA1 = lds + g1 * 8;
  uint16_t* dstB0 = lds + 8192 + g0 * 8;
  uint16_t* dstB1 = lds + 8192 + g1 * 8;

#define STAGE(tt)                                                            \
  do {                                                                       \
    const int _buf = (tt) & 3;                                               \
    const int _k0 = (tt) * BK;                                               \
    __builtin_amdgcn_global_load_lds(                                        \
        (const __attribute__((address_space(1))) void*)(srcA0 + _k0),        \
        (__attribute__((address_space(3))) void*)(dstA0 + _buf * 16384), 16, 0, 0); \
    __builtin_amdgcn_global_load_lds(                                        \
        (const __attribute__((address_space(1))) void*)(srcA1 + _k0),        \
        (__attribute__((address_space(3))) void*)(dstA1 + _buf * 16384), 16, 0, 0); \
    __builtin_amdgcn_global_load_lds(                                        \
        (const __attribute__((address_space(1))) void*)(srcB0 + _k0),        \
        (__attribute__((address_space(3))) void*)(dstB0 + _buf * 16384), 16, 0, 0); \
    __builtin_amdgcn_global_load_lds(                                        \
        (const __attribute__((address_space(1))) void*)(srcB1 + _k0),        \
        (__attribute__((address_space(3))) void*)(dstB1 + _buf * 16384), 16, 0, 0); \
  } while (0)

  // ---- ds_read fragment offsets (uint16 units), loop-invariant.
  int offA[8], offB[4];
#pragma unroll
  for (int m = 0; m < 8; ++m) {
    int r = wr * 128 + m * 16 + wl;
    int s = (r + (r >> 2)) & 3;
    offA[m] = (r * 4 + (kg ^ s)) * 8;
  }
#pragma unroll
  for (int n = 0; n < 4; ++n) {
    int r = wc * 64 + n * 16 + wl;
    int s = (r + (r >> 2)) & 3;
    offB[n] = 8192 + (r * 4 + (kg ^ s)) * 8;
  }

  f32x4 acc[8][4] = {};

  // ---- prologue: stage tiles 0,1,2 (12 loads); wait tile 0 (vmcnt 8)
#pragma unroll
  for (int pt = 0; pt < 3; ++pt) {
    if (pt < nK) STAGE(pt);
  }
  asm volatile("s_waitcnt vmcnt(8)" ::: "memory");
  __builtin_amdgcn_s_barrier();
  __builtin_amdgcn_sched_barrier(0);

  for (int t = 0; t < nK; ++t) {
    const uint16_t* bufp = lds + (t & 3) * 16384;

    // issue next-tile staging first (VMEM in flight across the whole tile)
    if ((t + 3) < nK) STAGE(t + 3);

    // issue all 12 ds_reads; compiler interleaves lgkm waits with MFMA
    bf16x8 af[4], bf[4], ag[4];
#pragma unroll
    for (int m = 0; m < 4; ++m)
      af[m] = *reinterpret_cast<const bf16x8*>(bufp + offA[m]);
#pragma unroll
    for (int n = 0; n < 4; ++n)
      bf[n] = *reinterpret_cast<const bf16x8*>(bufp + offB[n]);
#pragma unroll
    for (int m = 0; m < 4; ++m)
      ag[m] = *reinterpret_cast<const bf16x8*>(bufp + offA[4 + m]);

    __builtin_amdgcn_s_setprio(1);
#pragma unroll
    for (int m = 0; m < 4; ++m)
#pragma unroll
      for (int n = 0; n < 4; ++n)
        acc[m][n] = __builtin_amdgcn_mfma_f32_16x16x32_bf16(af[m], bf[n], acc[m][n], 0, 0, 0);
#pragma unroll
    for (int m = 0; m < 4; ++m)
#pragma unroll
      for (int n = 0; n < 4; ++n)
        acc[4 + m][n] = __builtin_amdgcn_mfma_f32_16x16x32_bf16(ag[m], bf[n], acc[4 + m][n], 0, 0, 0);
    __builtin_amdgcn_s_setprio(0);

    // K-tile boundary: counted vmcnt (never 0 in steady state), ONE barrier
    if (t < nK - 3) {
      asm volatile("s_waitcnt vmcnt(8)" ::: "memory");
    } else if (t == nK - 3) {
      asm volatile("s_waitcnt vmcnt(4)" ::: "memory");
    } else if (t == nK - 2) {
      asm volatile("s_waitcnt vmcnt(0)" ::: "memory");
    }
    __builtin_amdgcn_s_barrier();
    __builtin_amdgcn_sched_barrier(0);
  }

  // ---- epilogue: C/D layout col=lane&15, row=(lane>>4)*4+reg
#pragma unroll
  for (int m = 0; m < 8; ++m)
#pragma unroll
    for (int n = 0; n < 4; ++n)
#pragma unroll
      for (int r = 0; r < 4; ++r) {
        const int row = row0 + wr * 128 + m * 16 + kg * 4 + r;
        const int col = col0 + wc * 64 + n * 16 + wl;
        __hip_bfloat16 bv = __float2bfloat16(acc[m][n][r]);
        C[(size_t)row * V + col] = *reinterpret_cast<const uint16_t*>(&bv);
      }
#undef STAGE
}

// ---------------------------------------------------------------- JSD rows
__device__ __forceinline__ void unpack8(uint4 v, float* f) {
  uint32_t w[4] = {v.x, v.y, v.z, v.w};
#pragma unroll
  for (int j = 0; j < 4; ++j) {
    union { uint32_t u; float x; } lo, hi;
    lo.u = (w[j] & 0xffffu) << 16;
    hi.u = w[j] & 0xffff0000u;
    f[2 * j] = lo.x;
    f[2 * j + 1] = hi.x;
  }
}

__device__ __forceinline__ float blockReduce(float v, bool isMax, float* sh) {
#pragma unroll
  for (int o = 32; o >= 1; o >>= 1) {
    float other = __shfl_xor(v, o, 64);
    v = isMax ? fmaxf(v, other) : (v + other);
  }
  const int w = threadIdx.x >> 6;
  __syncthreads();
  if ((threadIdx.x & 63) == 0) sh[w] = v;
  __syncthreads();
  float r = sh[0];
#pragma unroll
  for (int i = 1; i < 4; ++i) r = isMax ? fmaxf(r, sh[i]) : (r + sh[i]);
  return r;
}

__global__ __launch_bounds__(256) void jsd_rows_kernel(
    const uint16_t* __restrict__ SL, const uint16_t* __restrict__ TL,
    float* __restrict__ per_tok, int V) {
  __shared__ __align__(16) uint16_t rowS[32000];
  __shared__ __align__(16) uint16_t rowT[32000];
  __shared__ float red[4];

  const int t = threadIdx.x;
  const int row = blockIdx.x;
  const uint4* gS = reinterpret_cast<const uint4*>(SL + (size_t)row * V);
  const uint4* gT = reinterpret_cast<const uint4*>(TL + (size_t)row * V);
  uint4* lS = reinterpret_cast<uint4*>(rowS);
  uint4* lT = reinterpret_cast<uint4*>(rowT);
  const int nvec = V >> 3;  // 4000

  for (int i = t; i < nvec; i += 256) { lS[i] = gS[i]; lT[i] = gT[i]; }
  __syncthreads();

  float mS = -3.0e38f, mT = -3.0e38f;
  for (int i = t; i < nvec; i += 256) {
    float fs[8], ft[8];
    unpack8(lS[i], fs);
    unpack8(lT[i], ft);
#pragma unroll
    for (int j = 0; j < 8; ++j) { mS = fmaxf(mS, fs[j]); mT = fmaxf(mT, ft[j]); }
  }
  mS = blockReduce(mS, true, red);
  mT = blockReduce(mT, true, red);

  float sS = 0.f, sT = 0.f;
  for (int i = t; i < nvec; i += 256) {
    float fs[8], ft[8];
    unpack8(lS[i], fs);
    unpack8(lT[i], ft);
#pragma unroll
    for (int j = 0; j < 8; ++j) { sS += __expf(fs[j] - mS); sT += __expf(ft[j] - mT); }
  }
  sS = blockReduce(sS, false, red);
  sT = blockReduce(sT, false, red);
  const float lseS = mS + __logf(sS);
  const float lseT = mT + __logf(sT);

  float acc = 0.f;
  for (int i = t; i < nvec; i += 256) {
    float fs[8], ft[8];
    unpack8(lS[i], fs);
    unpack8(lT[i], ft);
#pragma unroll
    for (int j = 0; j < 8; ++j) {
      const float lq = fs[j] - lseS;
      const float lp = ft[j] - lseT;
      const float q = __expf(lq);
      const float p = __expf(lp);
      const float m = BETA * p + (1.f - BETA) * q;
      const float lm = __logf(m);
      acc += BETA * p * (lp - lm) + (1.f - BETA) * q * (lq - lm);
    }
  }
  acc = blockReduce(acc, false, red);
  if (t == 0) per_tok[row] = acc;
}

// ---------------------------------------------------------------- finalize
__global__ __launch_bounds__(256) void finalize_kernel(
    const float* __restrict__ per_tok, const int* __restrict__ tgt,
    float* __restrict__ out, int N) {
  __shared__ float redf[4];
  __shared__ int redi[4];
  float s = 0.f;
  int c = 0;
  for (int i = threadIdx.x; i < N; i += 256) {
    if (tgt[i] != IGNORE_INDEX) { s += per_tok[i]; c += 1; }
  }
#pragma unroll
  for (int o = 32; o >= 1; o >>= 1) {
    s += __shfl_xor(s, o, 64);
    c += __shfl_xor(c, o, 64);
  }
  const int w = threadIdx.x >> 6;
  if ((threadIdx.x & 63) == 0) { redf[w] = s; redi[w] = c; }
  __syncthreads();
  if (threadIdx.x == 0) {
    float st = 0.f;
    int ct = 0;
#pragma unroll
    for (int i = 0; i < 4; ++i) { st += redf[i]; ct += redi[i]; }
    out[0] = st / (float)(ct > 0 ? ct : 1);
  }
}

// ---------------------------------------------------------------- launch
extern "C" void kernel_launch(void* const* d_in, const int* in_sizes, int n_in,
                              void* d_out, int out_size, void* d_ws, size_t ws_size,
                              hipStream_t stream) {
  const float* student = (const float*)d_in[0];
  const float* W_s     = (const float*)d_in[1];
  const float* teacher = (const float*)d_in[2];
  const float* W_t     = (const float*)d_in[3];
  const int*   target  = (const int*)d_in[4];

  const int N  = in_sizes[4];            // 2048
  const int Hs = in_sizes[0] / N;        // 2048
  const int Ht = in_sizes[2] / N;        // 4096
  const int V  = in_sizes[1] / Hs;       // 32000

  char* ws = (char*)d_ws;
  size_t off = 0;
  auto alloc = [&](size_t bytes) -> void* {
    void* p = ws + off;
    off += (bytes + 255) & ~(size_t)255;
    return p;
  };
  uint16_t* Sbf  = (uint16_t*)alloc((size_t)N * Hs * 2);
  uint16_t* Wsbf = (uint16_t*)alloc((size_t)V * Hs * 2);
  uint16_t* Tbf  = (uint16_t*)alloc((size_t)N * Ht * 2);
  uint16_t* Wtbf = (uint16_t*)alloc((size_t)V * Ht * 2);
  uint16_t* slog = (uint16_t*)alloc((size_t)N * V * 2);
  uint16_t* tlog = (uint16_t*)alloc((size_t)N * V * 2);
  float* per_tok = (float*)alloc((size_t)N * sizeof(float));
  (void)ws_size;  // total ~681 MB

  f32_to_bf16_kernel<<<1024, 256, 0, stream>>>(student, Sbf, N * Hs);
  f32_to_bf16_kernel<<<2048, 256, 0, stream>>>(W_s, Wsbf, V * Hs);
  f32_to_bf16_kernel<<<1024, 256, 0, stream>>>(teacher, Tbf, N * Ht);
  f32_to_bf16_kernel<<<2048, 256, 0, stream>>>(W_t, Wtbf, V * Ht);

  const int RT = N / 256;   // 8
  const int CT = V / 256;   // 125
  gemm8_kernel<<<RT * CT, 512, 0, stream>>>(Sbf, Wsbf, slog, Hs, V, RT, CT);
  gemm8_kernel<<<RT * CT, 512, 0, stream>>>(Tbf, Wtbf, tlog, Ht, V, RT, CT);

  jsd_rows_kernel<<<N, 256, 0, stream>>>(slog, tlog, per_tok, V);
  finalize_kernel<<<1, 256, 0, stream>>>(per_tok, target, (float*)d_out, N);
}

// Round 4
// 1112.342 us; speedup vs baseline: 1.3687x; 1.0583x over previous
//
#include <hip/hip_runtime.h>
#include <hip/hip_bf16.h>
#include <stdint.h>

#define BETA 0.5f
#define IGNORE_INDEX (-100)

typedef short bf16x8 __attribute__((ext_vector_type(8)));
typedef float f32x4 __attribute__((ext_vector_type(4)));

// ---------------------------------------------------------------- converts
__global__ __launch_bounds__(256) void f32_to_bf16_kernel(
    const float* __restrict__ in, uint16_t* __restrict__ out, int n) {
  int i = (blockIdx.x * blockDim.x + threadIdx.x) * 4;
  const int stride = gridDim.x * blockDim.x * 4;
  for (; i < n; i += stride) {
    float4 v = *reinterpret_cast<const float4*>(in + i);
    __hip_bfloat16 b0 = __float2bfloat16(v.x);
    __hip_bfloat16 b1 = __float2bfloat16(v.y);
    __hip_bfloat16 b2 = __float2bfloat16(v.z);
    __hip_bfloat16 b3 = __float2bfloat16(v.w);
    ushort4 o;
    o.x = *reinterpret_cast<const uint16_t*>(&b0);
    o.y = *reinterpret_cast<const uint16_t*>(&b1);
    o.z = *reinterpret_cast<const uint16_t*>(&b2);
    o.w = *reinterpret_cast<const uint16_t*>(&b3);
    *reinterpret_cast<ushort4*>(out + i) = o;
  }
}

// ---------------------------------------------------------------- GEMM (NT)
// C[n][v] = sum_k A[n][k]*B[v][k].  256x256 tile, BK=64, 8 waves (2Mx4N),
// m201-style phase template: 4 phases per K-tile, each
//   {ds_read subtile | stage 1 half-tile -> bar -> lgkm(0) -> 16 MFMA -> bar}
// Quadrants: P1 Q(0,0)[12 reads], P2 Q(0,1)[4], P3 Q(1,1)[8], P4 Q(1,0)[0].
// Half-tile stages: A0,A1 of tile T+1 at P1,P2 (other buffer); B0,B1 of
// tile T+2 at P3,P4 (current buffer, but B reads retired by bar2(P2)).
// Counted vmcnt(4) once per tile at P4 (T3+T4); setprio (T5); granule XOR
// swizzle, both-sides (rule #21); XCD block swizzle (T1).
// LDS: 2 buf x (A 32K + B 32K) = 128 KiB. Halves: A0@0 A1@16K B0@32K B1@48K.

__global__ __launch_bounds__(512, 2) void gemm4ph_kernel(
    const uint16_t* __restrict__ A, const uint16_t* __restrict__ B,
    uint16_t* __restrict__ C, int K, int V, int RT, int CT) {
  __shared__ __align__(16) uint16_t lds[65536];

  const int nwg = RT * CT;
  int bidx = blockIdx.x;
  int L = ((nwg & 7) == 0) ? ((bidx & 7) * (nwg >> 3) + (bidx >> 3)) : bidx;
  const int rt = L % RT;
  const int ct = L / RT;
  const int row0 = rt * 256;
  const int col0 = ct * 256;

  const int i  = threadIdx.x;      // 0..511
  const int w  = i >> 6;
  const int l  = i & 63;
  const int wl = l & 15;
  const int kg = l >> 4;
  const int wr = w >> 2;           // wave row 0..1 (128 out rows)
  const int wc = w & 3;            // wave col 0..3 (64 out cols)

  const int nT = K >> 6;           // BK = 64

  // ---- staging precompute: thread i loads granules i and i+512 per half.
  // granule g: row r=g>>3, phys col cph=g&7; logical col = cph ^ (r&7).
  const int r0 = i >> 3;           // 0..63 (granule i); granule i+512 -> +64
  const int cph = i & 7;
  const int clog = cph ^ (r0 & 7); // same for both granules (64 = 0 mod 8)
  const uint16_t* aSrc = A + (size_t)(row0 + r0) * K + clog * 8;
  const uint16_t* bSrc = B + (size_t)(col0 + r0) * K + clog * 8;
  uint16_t* ldsu = lds;

#define GL(srcp, dstp)                                                     \
  __builtin_amdgcn_global_load_lds(                                        \
      (const __attribute__((address_space(1))) void*)(srcp),               \
      (__attribute__((address_space(3))) void*)(dstp), 16, 0, 0)

#define STAGE_A(TT, HH)                                                    \
  do {                                                                     \
    const uint16_t* _s = aSrc + (size_t)(HH) * 128 * K + (size_t)(TT) * 64;\
    uint16_t* _d = ldsu + (((TT) & 1) * 32768) + (HH) * 8192 + i * 8;      \
    GL(_s, _d); GL(_s + (size_t)64 * K, _d + 4096);                        \
  } while (0)

#define STAGE_B(TT, HH)                                                    \
  do {                                                                     \
    const uint16_t* _s = bSrc + (size_t)(HH) * 128 * K + (size_t)(TT) * 64;\
    uint16_t* _d = ldsu + (((TT) & 1) * 32768) + 16384 + (HH) * 8192 + i * 8; \
    GL(_s, _d); GL(_s + (size_t)64 * K, _d + 4096);                        \
  } while (0)

  // ---- ds_read byte offsets within a buffer (A-half = wave's wr; B-half =
  // wc>>1). Phys col = (slot*4+kg) ^ (wl&7); mh1: +8192 B; nh1: +4096 B.
  int offA[4][2], offB[2][2];
#pragma unroll
  for (int m = 0; m < 4; ++m) {
    const int rho = m * 16 + wl;
#pragma unroll
    for (int s = 0; s < 2; ++s)
      offA[m][s] = wr * 16384 + rho * 128 + (((s * 4 + kg) ^ (wl & 7)) * 16);
  }
#pragma unroll
  for (int n = 0; n < 2; ++n) {
    const int sig = (wc & 1) * 64 + n * 16 + wl;
#pragma unroll
    for (int s = 0; s < 2; ++s)
      offB[n][s] = 32768 + (wc >> 1) * 16384 + sig * 128 +
                   (((s * 4 + kg) ^ (wl & 7)) * 16);
  }

  f32x4 acc[8][4] = {};
  bf16x8 af[4][2], b0[2][2], b1[2][2];

  // ---- prologue: tile0 all halves + tile1 B-halves (12 loads), wait tile0
  STAGE_A(0, 0); STAGE_A(0, 1); STAGE_B(0, 0); STAGE_B(0, 1);
  if (nT > 1) {
    STAGE_B(1, 0); STAGE_B(1, 1);
    asm volatile("s_waitcnt vmcnt(4)" ::: "memory");
  } else {
    asm volatile("s_waitcnt vmcnt(0)" ::: "memory");
  }
  __builtin_amdgcn_s_barrier();
  __builtin_amdgcn_sched_barrier(0);

  for (int T = 0; T < nT; ++T) {
    const char* bb = (const char*)lds + (T & 1) * 65536;

    // ---------- P1: read A(mh0)+B(nh0) [12]; stage A0(T+1); Q(0,0)
#pragma unroll
    for (int m = 0; m < 4; ++m)
#pragma unroll
      for (int s = 0; s < 2; ++s)
        af[m][s] = *reinterpret_cast<const bf16x8*>(bb + offA[m][s]);
#pragma unroll
    for (int n = 0; n < 2; ++n)
#pragma unroll
      for (int s = 0; s < 2; ++s)
        b0[n][s] = *reinterpret_cast<const bf16x8*>(bb + offB[n][s]);
    if (T + 1 < nT) STAGE_A(T + 1, 0);
    asm volatile("s_waitcnt lgkmcnt(8)" ::: "memory");
    __builtin_amdgcn_s_barrier();
    asm volatile("s_waitcnt lgkmcnt(0)" ::: "memory");
    __builtin_amdgcn_sched_barrier(0);
    __builtin_amdgcn_s_setprio(1);
#pragma unroll
    for (int m = 0; m < 4; ++m)
#pragma unroll
      for (int n = 0; n < 2; ++n)
#pragma unroll
        for (int s = 0; s < 2; ++s)
          acc[m][n] = __builtin_amdgcn_mfma_f32_16x16x32_bf16(
              af[m][s], b0[n][s], acc[m][n], 0, 0, 0);
    __builtin_amdgcn_s_setprio(0);
    __builtin_amdgcn_s_barrier();

    // ---------- P2: read B(nh1) [4]; stage A1(T+1); Q(0,1)
#pragma unroll
    for (int n = 0; n < 2; ++n)
#pragma unroll
      for (int s = 0; s < 2; ++s)
        b1[n][s] = *reinterpret_cast<const bf16x8*>(bb + offB[n][s] + 4096);
    if (T + 1 < nT) STAGE_A(T + 1, 1);
    __builtin_amdgcn_s_barrier();
    asm volatile("s_waitcnt lgkmcnt(0)" ::: "memory");
    __builtin_amdgcn_sched_barrier(0);
    __builtin_amdgcn_s_setprio(1);
#pragma unroll
    for (int m = 0; m < 4; ++m)
#pragma unroll
      for (int n = 0; n < 2; ++n)
#pragma unroll
        for (int s = 0; s < 2; ++s)
          acc[m][2 + n] = __builtin_amdgcn_mfma_f32_16x16x32_bf16(
              af[m][s], b1[n][s], acc[m][2 + n], 0, 0, 0);
    __builtin_amdgcn_s_setprio(0);
    __builtin_amdgcn_s_barrier();

    // ---------- P3: read A(mh1) [8]; stage B0(T+2); Q(1,1)
#pragma unroll
    for (int m = 0; m < 4; ++m)
#pragma unroll
      for (int s = 0; s < 2; ++s)
        af[m][s] = *reinterpret_cast<const bf16x8*>(bb + offA[m][s] + 8192);
    if (T + 2 < nT) STAGE_B(T + 2, 0);
    __builtin_amdgcn_s_barrier();
    asm volatile("s_waitcnt lgkmcnt(0)" ::: "memory");
    __builtin_amdgcn_sched_barrier(0);
    __builtin_amdgcn_s_setprio(1);
#pragma unroll
    for (int m = 0; m < 4; ++m)
#pragma unroll
      for (int n = 0; n < 2; ++n)
#pragma unroll
        for (int s = 0; s < 2; ++s)
          acc[4 + m][2 + n] = __builtin_amdgcn_mfma_f32_16x16x32_bf16(
              af[m][s], b1[n][s], acc[4 + m][2 + n], 0, 0, 0);
    __builtin_amdgcn_s_setprio(0);
    __builtin_amdgcn_s_barrier();

    // ---------- P4: stage B1(T+2); Q(1,0); counted vmcnt at tile boundary
    if (T + 2 < nT) STAGE_B(T + 2, 1);
    __builtin_amdgcn_s_barrier();
    __builtin_amdgcn_s_setprio(1);
#pragma unroll
    for (int m = 0; m < 4; ++m)
#pragma unroll
      for (int n = 0; n < 2; ++n)
#pragma unroll
        for (int s = 0; s < 2; ++s)
          acc[4 + m][n] = __builtin_amdgcn_mfma_f32_16x16x32_bf16(
              af[m][s], b0[n][s], acc[4 + m][n], 0, 0, 0);
    __builtin_amdgcn_s_setprio(0);
    if (T + 2 < nT) {
      asm volatile("s_waitcnt vmcnt(4)" ::: "memory");
    } else {
      asm volatile("s_waitcnt vmcnt(0)" ::: "memory");
    }
    __builtin_amdgcn_s_barrier();
    __builtin_amdgcn_sched_barrier(0);
  }

  // ---- epilogue: C/D layout col=lane&15, row=(lane>>4)*4+reg
#pragma unroll
  for (int mg = 0; mg < 8; ++mg)
#pragma unroll
    for (int ng = 0; ng < 4; ++ng)
#pragma unroll
      for (int r = 0; r < 4; ++r) {
        const int row = row0 + wr * 128 + mg * 16 + kg * 4 + r;
        const int col = col0 + wc * 64 + ng * 16 + wl;
        __hip_bfloat16 bv = __float2bfloat16(acc[mg][ng][r]);
        C[(size_t)row * V + col] = *reinterpret_cast<const uint16_t*>(&bv);
      }
#undef STAGE_A
#undef STAGE_B
#undef GL
}

// ---------------------------------------------------------------- JSD rows
__device__ __forceinline__ void unpack8(uint4 v, float* f) {
  uint32_t w[4] = {v.x, v.y, v.z, v.w};
#pragma unroll
  for (int j = 0; j < 4; ++j) {
    union { uint32_t u; float x; } lo, hi;
    lo.u = (w[j] & 0xffffu) << 16;
    hi.u = w[j] & 0xffff0000u;
    f[2 * j] = lo.x;
    f[2 * j + 1] = hi.x;
  }
}

__device__ __forceinline__ float blockReduce(float v, bool isMax, float* sh) {
#pragma unroll
  for (int o = 32; o >= 1; o >>= 1) {
    float other = __shfl_xor(v, o, 64);
    v = isMax ? fmaxf(v, other) : (v + other);
  }
  const int w = threadIdx.x >> 6;
  __syncthreads();
  if ((threadIdx.x & 63) == 0) sh[w] = v;
  __syncthreads();
  float r = sh[0];
#pragma unroll
  for (int i = 1; i < 4; ++i) r = isMax ? fmaxf(r, sh[i]) : (r + sh[i]);
  return r;
}

__global__ __launch_bounds__(256) void jsd_rows_kernel(
    const uint16_t* __restrict__ SL, const uint16_t* __restrict__ TL,
    float* __restrict__ per_tok, int V) {
  __shared__ __align__(16) uint16_t rowS[32000];
  __shared__ __align__(16) uint16_t rowT[32000];
  __shared__ float red[4];

  const int t = threadIdx.x;
  const int row = blockIdx.x;
  const uint4* gS = reinterpret_cast<const uint4*>(SL + (size_t)row * V);
  const uint4* gT = reinterpret_cast<const uint4*>(TL + (size_t)row * V);
  uint4* lS = reinterpret_cast<uint4*>(rowS);
  uint4* lT = reinterpret_cast<uint4*>(rowT);
  const int nvec = V >> 3;  // 4000

  for (int i = t; i < nvec; i += 256) { lS[i] = gS[i]; lT[i] = gT[i]; }
  __syncthreads();

  float mS = -3.0e38f, mT = -3.0e38f;
  for (int i = t; i < nvec; i += 256) {
    float fs[8], ft[8];
    unpack8(lS[i], fs);
    unpack8(lT[i], ft);
#pragma unroll
    for (int j = 0; j < 8; ++j) { mS = fmaxf(mS, fs[j]); mT = fmaxf(mT, ft[j]); }
  }
  mS = blockReduce(mS, true, red);
  mT = blockReduce(mT, true, red);

  float sS = 0.f, sT = 0.f;
  for (int i = t; i < nvec; i += 256) {
    float fs[8], ft[8];
    unpack8(lS[i], fs);
    unpack8(lT[i], ft);
#pragma unroll
    for (int j = 0; j < 8; ++j) { sS += __expf(fs[j] - mS); sT += __expf(ft[j] - mT); }
  }
  sS = blockReduce(sS, false, red);
  sT = blockReduce(sT, false, red);
  const float lseS = mS + __logf(sS);
  const float lseT = mT + __logf(sT);

  float acc = 0.f;
  for (int i = t; i < nvec; i += 256) {
    float fs[8], ft[8];
    unpack8(lS[i], fs);
    unpack8(lT[i], ft);
#pragma unroll
    for (int j = 0; j < 8; ++j) {
      const float lq = fs[j] - lseS;
      const float lp = ft[j] - lseT;
      const float q = __expf(lq);
      const float p = __expf(lp);
      const float m = BETA * p + (1.f - BETA) * q;
      const float lm = __logf(m);
      acc += BETA * p * (lp - lm) + (1.f - BETA) * q * (lq - lm);
    }
  }
  acc = blockReduce(acc, false, red);
  if (t == 0) per_tok[row] = acc;
}

// ---------------------------------------------------------------- finalize
__global__ __launch_bounds__(256) void finalize_kernel(
    const float* __restrict__ per_tok, const int* __restrict__ tgt,
    float* __restrict__ out, int N) {
  __shared__ float redf[4];
  __shared__ int redi[4];
  float s = 0.f;
  int c = 0;
  for (int i = threadIdx.x; i < N; i += 256) {
    if (tgt[i] != IGNORE_INDEX) { s += per_tok[i]; c += 1; }
  }
#pragma unroll
  for (int o = 32; o >= 1; o >>= 1) {
    s += __shfl_xor(s, o, 64);
    c += __shfl_xor(c, o, 64);
  }
  const int w = threadIdx.x >> 6;
  if ((threadIdx.x & 63) == 0) { redf[w] = s; redi[w] = c; }
  __syncthreads();
  if (threadIdx.x == 0) {
    float st = 0.f;
    int ct = 0;
#pragma unroll
    for (int i = 0; i < 4; ++i) { st += redf[i]; ct += redi[i]; }
    out[0] = st / (float)(ct > 0 ? ct : 1);
  }
}

// ---------------------------------------------------------------- launch
extern "C" void kernel_launch(void* const* d_in, const int* in_sizes, int n_in,
                              void* d_out, int out_size, void* d_ws, size_t ws_size,
                              hipStream_t stream) {
  const float* student = (const float*)d_in[0];
  const float* W_s     = (const float*)d_in[1];
  const float* teacher = (const float*)d_in[2];
  const float* W_t     = (const float*)d_in[3];
  const int*   target  = (const int*)d_in[4];

  const int N  = in_sizes[4];            // 2048
  const int Hs = in_sizes[0] / N;        // 2048
  const int Ht = in_sizes[2] / N;        // 4096
  const int V  = in_sizes[1] / Hs;       // 32000

  char* ws = (char*)d_ws;
  size_t off = 0;
  auto alloc = [&](size_t bytes) -> void* {
    void* p = ws + off;
    off += (bytes + 255) & ~(size_t)255;
    return p;
  };
  uint16_t* Sbf  = (uint16_t*)alloc((size_t)N * Hs * 2);
  uint16_t* Wsbf = (uint16_t*)alloc((size_t)V * Hs * 2);
  uint16_t* Tbf  = (uint16_t*)alloc((size_t)N * Ht * 2);
  uint16_t* Wtbf = (uint16_t*)alloc((size_t)V * Ht * 2);
  uint16_t* slog = (uint16_t*)alloc((size_t)N * V * 2);
  uint16_t* tlog = (uint16_t*)alloc((size_t)N * V * 2);
  float* per_tok = (float*)alloc((size_t)N * sizeof(float));
  (void)ws_size;  // total ~681 MB

  f32_to_bf16_kernel<<<1024, 256, 0, stream>>>(student, Sbf, N * Hs);
  f32_to_bf16_kernel<<<2048, 256, 0, stream>>>(W_s, Wsbf, V * Hs);
  f32_to_bf16_kernel<<<1024, 256, 0, stream>>>(teacher, Tbf, N * Ht);
  f32_to_bf16_kernel<<<2048, 256, 0, stream>>>(W_t, Wtbf, V * Ht);

  const int RT = N / 256;   // 8
  const int CT = V / 256;   // 125
  gemm4ph_kernel<<<RT * CT, 512, 0, stream>>>(Sbf, Wsbf, slog, Hs, V, RT, CT);
  gemm4ph_kernel<<<RT * CT, 512, 0, stream>>>(Tbf, Wtbf, tlog, Ht, V, RT, CT);

  jsd_rows_kernel<<<N, 256, 0, stream>>>(slog, tlog, per_tok, V);
  finalize_kernel<<<1, 256, 0, stream>>>(per_tok, target, (float*)d_out, N);
}

// Round 5
// 1110.307 us; speedup vs baseline: 1.3713x; 1.0018x over previous
//
#include <hip/hip_runtime.h>
#include <hip/hip_bf16.h>
#include <stdint.h>

#define BETA 0.5f
#define IGNORE_INDEX (-100)

typedef short bf16x8 __attribute__((ext_vector_type(8)));
typedef float f32x4 __attribute__((ext_vector_type(4)));

// ---------------------------------------------------------------- converts
__global__ __launch_bounds__(256) void f32_to_bf16_kernel(
    const float* __restrict__ in, uint16_t* __restrict__ out, int n) {
  int i = (blockIdx.x * blockDim.x + threadIdx.x) * 4;
  const int stride = gridDim.x * blockDim.x * 4;
  for (; i < n; i += stride) {
    float4 v = *reinterpret_cast<const float4*>(in + i);
    __hip_bfloat16 b0 = __float2bfloat16(v.x);
    __hip_bfloat16 b1 = __float2bfloat16(v.y);
    __hip_bfloat16 b2 = __float2bfloat16(v.z);
    __hip_bfloat16 b3 = __float2bfloat16(v.w);
    ushort4 o;
    o.x = *reinterpret_cast<const uint16_t*>(&b0);
    o.y = *reinterpret_cast<const uint16_t*>(&b1);
    o.z = *reinterpret_cast<const uint16_t*>(&b2);
    o.w = *reinterpret_cast<const uint16_t*>(&b3);
    *reinterpret_cast<ushort4*>(out + i) = o;
  }
}

// ---------------------------------------------------------------- GEMM (NT)
// C[n][v] = sum_k A[n][k]*B[v][k].  256x256 tile, BK=64, 8 waves (2Mx4N),
// 4 phases per K-tile split by (M-half x k-slot) -> balanced 8/4/8/4
// ds_reads/phase (m201 pattern).  Per phase:
//   {ds_reads | stage -> bar -> lgkm(0) -> setprio+16 MFMA -> [vmcnt] -> bar}
// Stages: A0(T+1)@P1, A1(T+1)@P2 (other buffer); B0+B1(T+2)@P4 (current
// buffer, B reads globally retired at P3-bar2).  Boundary vmcnt(4) drains
// tile T+1, leaves B(T+2) in flight (T3+T4).  setprio (T5), granule XOR
// swizzle both-sides (rule #21), per-half XCD swizzle (T1).
// LDS: 2 buf x (A 32K + B 32K) = 128 KiB.
// Merged launch: blocks [0,half) = teacher, [half,2*half) = student.

__global__ __launch_bounds__(512, 2) void gemm4ph_kernel(
    const uint16_t* __restrict__ At, const uint16_t* __restrict__ Bt,
    uint16_t* __restrict__ Ct, int Kt,
    const uint16_t* __restrict__ As_, const uint16_t* __restrict__ Bs_,
    uint16_t* __restrict__ Cs, int Ks,
    int V, int RT, int CT) {
  __shared__ __align__(16) uint16_t lds[65536];

  const int half = RT * CT;
  const uint16_t *A, *B;
  uint16_t* C;
  int K, bidx = blockIdx.x;
  if (bidx < half) { A = At; B = Bt; C = Ct; K = Kt; }
  else             { A = As_; B = Bs_; C = Cs; K = Ks; bidx -= half; }

  int L = ((half & 7) == 0) ? ((bidx & 7) * (half >> 3) + (bidx >> 3)) : bidx;
  const int rt = L % RT;
  const int ct = L / RT;
  const int row0 = rt * 256;
  const int col0 = ct * 256;

  const int i  = threadIdx.x;      // 0..511
  const int w  = i >> 6;
  const int l  = i & 63;
  const int wl = l & 15;
  const int kg = l >> 4;
  const int wr = w >> 2;           // wave row 0..1 (128 out rows)
  const int wc = w & 3;            // wave col 0..3 (64 out cols)

  const int nT = K >> 6;           // BK = 64

  // ---- staging: thread i loads granules i and i+512 per half-tile.
  // granule g: row r=g>>3, phys col=g&7; logical col = phys ^ (r&7).
  const int r0 = i >> 3;
  const int cph = i & 7;
  const int clog = cph ^ (r0 & 7);
  const uint16_t* aSrc = A + (size_t)(row0 + r0) * K + clog * 8;
  const uint16_t* bSrc = B + (size_t)(col0 + r0) * K + clog * 8;
  uint16_t* ldsu = lds;

#define GL(srcp, dstp)                                                     \
  __builtin_amdgcn_global_load_lds(                                        \
      (const __attribute__((address_space(1))) void*)(srcp),               \
      (__attribute__((address_space(3))) void*)(dstp), 16, 0, 0)

#define STAGE_A(TT, HH)                                                    \
  do {                                                                     \
    const uint16_t* _s = aSrc + (size_t)(HH) * 128 * K + (size_t)(TT) * 64;\
    uint16_t* _d = ldsu + (((TT) & 1) * 32768) + (HH) * 8192 + i * 8;      \
    GL(_s, _d); GL(_s + (size_t)64 * K, _d + 4096);                        \
  } while (0)

#define STAGE_B(TT, HH)                                                    \
  do {                                                                     \
    const uint16_t* _s = bSrc + (size_t)(HH) * 128 * K + (size_t)(TT) * 64;\
    uint16_t* _d = ldsu + (((TT) & 1) * 32768) + 16384 + (HH) * 8192 + i * 8; \
    GL(_s, _d); GL(_s + (size_t)64 * K, _d + 4096);                        \
  } while (0)

  // ---- ds_read byte offsets (A-half = wr; B-half = wc>>1).
  // phys col = (slot*4+kg) ^ (wl&7).
  int offA[8][2], offB[4][2];
#pragma unroll
  for (int m = 0; m < 8; ++m) {
    const int rho = (m & 3) * 16 + wl;        // row within half-of-half
    const int mh = m >> 2;                    // 0: rows 0..63, 1: 64..127
#pragma unroll
    for (int s = 0; s < 2; ++s)
      offA[m][s] = wr * 16384 + mh * 8192 + rho * 128 +
                   (((s * 4 + kg) ^ (wl & 7)) * 16);
  }
#pragma unroll
  for (int n = 0; n < 4; ++n) {
    const int sig = (wc & 1) * 64 + n * 16 + wl;
#pragma unroll
    for (int s = 0; s < 2; ++s)
      offB[n][s] = 32768 + (wc >> 1) * 16384 + sig * 128 +
                   (((s * 4 + kg) ^ (wl & 7)) * 16);
  }

  f32x4 acc[8][4] = {};
  bf16x8 af[4], bf[4], ag[4];

  // ---- prologue: tile0 all halves + tile1 B halves; drain tile0
  STAGE_A(0, 0); STAGE_A(0, 1); STAGE_B(0, 0); STAGE_B(0, 1);
  if (nT > 1) {
    STAGE_B(1, 0); STAGE_B(1, 1);
    asm volatile("s_waitcnt vmcnt(4)" ::: "memory");
  } else {
    asm volatile("s_waitcnt vmcnt(0)" ::: "memory");
  }
  __builtin_amdgcn_s_barrier();
  __builtin_amdgcn_sched_barrier(0);

  for (int T = 0; T < nT; ++T) {
    const char* bb = (const char*)lds + (T & 1) * 65536;
    const bool stg1 = (T + 1) < nT;
    const bool stg2 = (T + 2) < nT;

    // ---------- P1: read A(mh0,s0)[4] + B(s0)[4]; stage A0(T+1); MFMA m0..3 s0
#pragma unroll
    for (int m = 0; m < 4; ++m)
      af[m] = *reinterpret_cast<const bf16x8*>(bb + offA[m][0]);
#pragma unroll
    for (int n = 0; n < 4; ++n)
      bf[n] = *reinterpret_cast<const bf16x8*>(bb + offB[n][0]);
    if (stg1) STAGE_A(T + 1, 0);
    __builtin_amdgcn_s_barrier();
    asm volatile("s_waitcnt lgkmcnt(0)" ::: "memory");
    __builtin_amdgcn_sched_barrier(0);
    __builtin_amdgcn_s_setprio(1);
#pragma unroll
    for (int m = 0; m < 4; ++m)
#pragma unroll
      for (int n = 0; n < 4; ++n)
        acc[m][n] = __builtin_amdgcn_mfma_f32_16x16x32_bf16(
            af[m], bf[n], acc[m][n], 0, 0, 0);
    __builtin_amdgcn_s_setprio(0);
    __builtin_amdgcn_s_barrier();

    // ---------- P2: read A(mh1,s0)[4]; stage A1(T+1); MFMA m4..7 s0 (reuse bf)
#pragma unroll
    for (int m = 0; m < 4; ++m)
      ag[m] = *reinterpret_cast<const bf16x8*>(bb + offA[4 + m][0]);
    if (stg1) STAGE_A(T + 1, 1);
    __builtin_amdgcn_s_barrier();
    asm volatile("s_waitcnt lgkmcnt(0)" ::: "memory");
    __builtin_amdgcn_sched_barrier(0);
    __builtin_amdgcn_s_setprio(1);
#pragma unroll
    for (int m = 0; m < 4; ++m)
#pragma unroll
      for (int n = 0; n < 4; ++n)
        acc[4 + m][n] = __builtin_amdgcn_mfma_f32_16x16x32_bf16(
            ag[m], bf[n], acc[4 + m][n], 0, 0, 0);
    __builtin_amdgcn_s_setprio(0);
    __builtin_amdgcn_s_barrier();

    // ---------- P3: read A(mh0,s1)[4] + B(s1)[4]; MFMA m0..3 s1
#pragma unroll
    for (int m = 0; m < 4; ++m)
      af[m] = *reinterpret_cast<const bf16x8*>(bb + offA[m][1]);
#pragma unroll
    for (int n = 0; n < 4; ++n)
      bf[n] = *reinterpret_cast<const bf16x8*>(bb + offB[n][1]);
    __builtin_amdgcn_s_barrier();
    asm volatile("s_waitcnt lgkmcnt(0)" ::: "memory");
    __builtin_amdgcn_sched_barrier(0);
    __builtin_amdgcn_s_setprio(1);
#pragma unroll
    for (int m = 0; m < 4; ++m)
#pragma unroll
      for (int n = 0; n < 4; ++n)
        acc[m][n] = __builtin_amdgcn_mfma_f32_16x16x32_bf16(
            af[m], bf[n], acc[m][n], 0, 0, 0);
    __builtin_amdgcn_s_setprio(0);
    __builtin_amdgcn_s_barrier();

    // ---------- P4: read A(mh1,s1)[4]; stage B0+B1(T+2); MFMA m4..7 s1;
    //              boundary counted vmcnt
#pragma unroll
    for (int m = 0; m < 4; ++m)
      ag[m] = *reinterpret_cast<const bf16x8*>(bb + offA[4 + m][1]);
    if (stg2) { STAGE_B(T + 2, 0); STAGE_B(T + 2, 1); }
    __builtin_amdgcn_s_barrier();
    asm volatile("s_waitcnt lgkmcnt(0)" ::: "memory");
    __builtin_amdgcn_sched_barrier(0);
    __builtin_amdgcn_s_setprio(1);
#pragma unroll
    for (int m = 0; m < 4; ++m)
#pragma unroll
      for (int n = 0; n < 4; ++n)
        acc[4 + m][n] = __builtin_amdgcn_mfma_f32_16x16x32_bf16(
            ag[m], bf[n], acc[4 + m][n], 0, 0, 0);
    __builtin_amdgcn_s_setprio(0);
    if (stg2) {
      asm volatile("s_waitcnt vmcnt(4)" ::: "memory");
    } else {
      asm volatile("s_waitcnt vmcnt(0)" ::: "memory");
    }
    __builtin_amdgcn_s_barrier();
    __builtin_amdgcn_sched_barrier(0);
  }

  // ---- epilogue: C/D layout col=lane&15, row=(lane>>4)*4+reg
#pragma unroll
  for (int mg = 0; mg < 8; ++mg)
#pragma unroll
    for (int ng = 0; ng < 4; ++ng)
#pragma unroll
      for (int r = 0; r < 4; ++r) {
        const int row = row0 + wr * 128 + mg * 16 + kg * 4 + r;
        const int col = col0 + wc * 64 + ng * 16 + wl;
        __hip_bfloat16 bv = __float2bfloat16(acc[mg][ng][r]);
        C[(size_t)row * V + col] = *reinterpret_cast<const uint16_t*>(&bv);
      }
#undef STAGE_A
#undef STAGE_B
#undef GL
}

// ---------------------------------------------------------------- JSD rows
__device__ __forceinline__ void unpack8(uint4 v, float* f) {
  uint32_t w[4] = {v.x, v.y, v.z, v.w};
#pragma unroll
  for (int j = 0; j < 4; ++j) {
    union { uint32_t u; float x; } lo, hi;
    lo.u = (w[j] & 0xffffu) << 16;
    hi.u = w[j] & 0xffff0000u;
    f[2 * j] = lo.x;
    f[2 * j + 1] = hi.x;
  }
}

__device__ __forceinline__ float blockReduce(float v, bool isMax, float* sh) {
#pragma unroll
  for (int o = 32; o >= 1; o >>= 1) {
    float other = __shfl_xor(v, o, 64);
    v = isMax ? fmaxf(v, other) : (v + other);
  }
  const int w = threadIdx.x >> 6;
  __syncthreads();
  if ((threadIdx.x & 63) == 0) sh[w] = v;
  __syncthreads();
  float r = sh[0];
#pragma unroll
  for (int i = 1; i < 4; ++i) r = isMax ? fmaxf(r, sh[i]) : (r + sh[i]);
  return r;
}

__global__ __launch_bounds__(256) void jsd_rows_kernel(
    const uint16_t* __restrict__ SL, const uint16_t* __restrict__ TL,
    float* __restrict__ per_tok, int V) {
  __shared__ __align__(16) uint16_t rowS[32000];
  __shared__ __align__(16) uint16_t rowT[32000];
  __shared__ float red[4];

  const int t = threadIdx.x;
  const int row = blockIdx.x;
  const uint4* gS = reinterpret_cast<const uint4*>(SL + (size_t)row * V);
  const uint4* gT = reinterpret_cast<const uint4*>(TL + (size_t)row * V);
  uint4* lS = reinterpret_cast<uint4*>(rowS);
  uint4* lT = reinterpret_cast<uint4*>(rowT);
  const int nvec = V >> 3;  // 4000

  for (int i = t; i < nvec; i += 256) { lS[i] = gS[i]; lT[i] = gT[i]; }
  __syncthreads();

  float mS = -3.0e38f, mT = -3.0e38f;
  for (int i = t; i < nvec; i += 256) {
    float fs[8], ft[8];
    unpack8(lS[i], fs);
    unpack8(lT[i], ft);
#pragma unroll
    for (int j = 0; j < 8; ++j) { mS = fmaxf(mS, fs[j]); mT = fmaxf(mT, ft[j]); }
  }
  mS = blockReduce(mS, true, red);
  mT = blockReduce(mT, true, red);

  float sS = 0.f, sT = 0.f;
  for (int i = t; i < nvec; i += 256) {
    float fs[8], ft[8];
    unpack8(lS[i], fs);
    unpack8(lT[i], ft);
#pragma unroll
    for (int j = 0; j < 8; ++j) { sS += __expf(fs[j] - mS); sT += __expf(ft[j] - mT); }
  }
  sS = blockReduce(sS, false, red);
  sT = blockReduce(sT, false, red);
  const float lseS = mS + __logf(sS);
  const float lseT = mT + __logf(sT);

  float acc = 0.f;
  for (int i = t; i < nvec; i += 256) {
    float fs[8], ft[8];
    unpack8(lS[i], fs);
    unpack8(lT[i], ft);
#pragma unroll
    for (int j = 0; j < 8; ++j) {
      const float lq = fs[j] - lseS;
      const float lp = ft[j] - lseT;
      const float q = __expf(lq);
      const float p = __expf(lp);
      const float m = BETA * p + (1.f - BETA) * q;
      const float lm = __logf(m);
      acc += BETA * p * (lp - lm) + (1.f - BETA) * q * (lq - lm);
    }
  }
  acc = blockReduce(acc, false, red);
  if (t == 0) per_tok[row] = acc;
}

// ---------------------------------------------------------------- finalize
__global__ __launch_bounds__(256) void finalize_kernel(
    const float* __restrict__ per_tok, const int* __restrict__ tgt,
    float* __restrict__ out, int N) {
  __shared__ float redf[4];
  __shared__ int redi[4];
  float s = 0.f;
  int c = 0;
  for (int i = threadIdx.x; i < N; i += 256) {
    if (tgt[i] != IGNORE_INDEX) { s += per_tok[i]; c += 1; }
  }
#pragma unroll
  for (int o = 32; o >= 1; o >>= 1) {
    s += __shfl_xor(s, o, 64);
    c += __shfl_xor(c, o, 64);
  }
  const int w = threadIdx.x >> 6;
  if ((threadIdx.x & 63) == 0) { redf[w] = s; redi[w] = c; }
  __syncthreads();
  if (threadIdx.x == 0) {
    float st = 0.f;
    int ct = 0;
#pragma unroll
    for (int i = 0; i < 4; ++i) { st += redf[i]; ct += redi[i]; }
    out[0] = st / (float)(ct > 0 ? ct : 1);
  }
}

// ---------------------------------------------------------------- launch
extern "C" void kernel_launch(void* const* d_in, const int* in_sizes, int n_in,
                              void* d_out, int out_size, void* d_ws, size_t ws_size,
                              hipStream_t stream) {
  const float* student = (const float*)d_in[0];
  const float* W_s     = (const float*)d_in[1];
  const float* teacher = (const float*)d_in[2];
  const float* W_t     = (const float*)d_in[3];
  const int*   target  = (const int*)d_in[4];

  const int N  = in_sizes[4];            // 2048
  const int Hs = in_sizes[0] / N;        // 2048
  const int Ht = in_sizes[2] / N;        // 4096
  const int V  = in_sizes[1] / Hs;       // 32000

  char* ws = (char*)d_ws;
  size_t off = 0;
  auto alloc = [&](size_t bytes) -> void* {
    void* p = ws + off;
    off += (bytes + 255) & ~(size_t)255;
    return p;
  };
  uint16_t* Sbf  = (uint16_t*)alloc((size_t)N * Hs * 2);
  uint16_t* Wsbf = (uint16_t*)alloc((size_t)V * Hs * 2);
  uint16_t* Tbf  = (uint16_t*)alloc((size_t)N * Ht * 2);
  uint16_t* Wtbf = (uint16_t*)alloc((size_t)V * Ht * 2);
  uint16_t* slog = (uint16_t*)alloc((size_t)N * V * 2);
  uint16_t* tlog = (uint16_t*)alloc((size_t)N * V * 2);
  float* per_tok = (float*)alloc((size_t)N * sizeof(float));
  (void)ws_size;  // total ~681 MB

  f32_to_bf16_kernel<<<1024, 256, 0, stream>>>(student, Sbf, N * Hs);
  f32_to_bf16_kernel<<<2048, 256, 0, stream>>>(W_s, Wsbf, V * Hs);
  f32_to_bf16_kernel<<<1024, 256, 0, stream>>>(teacher, Tbf, N * Ht);
  f32_to_bf16_kernel<<<2048, 256, 0, stream>>>(W_t, Wtbf, V * Ht);

  const int RT = N / 256;   // 8
  const int CT = V / 256;   // 125
  // merged launch: teacher blocks first, student backfills the tail
  gemm4ph_kernel<<<2 * RT * CT, 512, 0, stream>>>(
      Tbf, Wtbf, tlog, Ht, Sbf, Wsbf, slog, Hs, V, RT, CT);

  jsd_rows_kernel<<<N, 256, 0, stream>>>(slog, tlog, per_tok, V);
  finalize_kernel<<<1, 256, 0, stream>>>(per_tok, target, (float*)d_out, N);
}